// Round 6
// baseline (9493.410 us; speedup 1.0000x reference)
//
#include <hip/hip_runtime.h>
#include <hip/hip_bf16.h>

typedef __attribute__((ext_vector_type(4))) float f32x4;
typedef __attribute__((ext_vector_type(8))) short s16x8;
typedef __attribute__((ext_vector_type(4))) short s16x4;

#define DI __device__ __forceinline__

static constexpr int B_ = 8, S_ = 2048, E_ = 300, EP_ = 320, HD_ = 512, G4_ = 2048;
static constexpr int C_ = 8921, RNN_ = 1024, NROW_ = 16384;

DI float bf2f(unsigned short u){ unsigned int x = ((unsigned int)u) << 16; return __builtin_bit_cast(float, x); }
DI unsigned short f2bf(float f){
  unsigned int x = __builtin_bit_cast(unsigned int, f);
  x += 0x7fff + ((x >> 16) & 1);
  return (unsigned short)(x >> 16);
}
DI float sigm(float x){ return 1.f / (1.f + __expf(-x)); }
DI float tanh_f(float x){
  x = fminf(fmaxf(x, -15.f), 15.f);
  float e = __expf(2.f * x);
  return (e - 1.f) / (e + 1.f);
}
DI void gload16(const void* g, void* l){
  __builtin_amdgcn_global_load_lds((const __attribute__((address_space(1))) void*)g,
                                   (__attribute__((address_space(3))) void*)l, 16, 0, 0);
}
DI unsigned pmax16(unsigned a, unsigned b){
  unsigned r; asm("v_pk_max_u16 %0, %1, %2" : "=v"(r) : "v"(a), "v"(b)); return r;
}
DI unsigned pmax4(uint4 v){ return pmax16(pmax16(v.x, v.y), pmax16(v.z, v.w)); }

// ---------------- convert / pad fp32 -> bf16 ----------------
__global__ void k_cvt_pad(const float* __restrict__ src, unsigned short* __restrict__ dst,
                          int Rs, int Cs, int Cd){
  int r = blockIdx.x;
  long db = (long)r * Cd;
  for (int c = threadIdx.x; c < Cd; c += blockDim.x){
    float v = (r < Rs && c < Cs) ? src[(long)r * Cs + c] : 0.f;
    dst[db + c] = f2bf(v);
  }
}

// ---------------- embedding gather -> xe [S][B][EP] bf16 ----------------
__global__ void k_embed(const int* __restrict__ text, const float* __restrict__ emb,
                        unsigned short* __restrict__ xe){
  int m = blockIdx.x;            // m = s*8 + b
  int s = m >> 3, b = m & 7;
  int tok = text[b * S_ + s];
  const float* e = emb + (long)tok * E_;
  long db = (long)m * EP_;
  for (int c = threadIdx.x; c < EP_; c += blockDim.x){
    float v = (c < E_) ? e[c] : 0.f;
    xe[db + c] = f2bf(v);
  }
}

// ---------------- gemm_bt: C[M,N] = A[M,K] * Bt[N,K]^T  (bf16 in, fp32 acc) --------
// EPI: 0 = fp32 store, 1 = bf16 tanh, 2 = bf16 + bias, 3 = bf16
template<int EPI>
__global__ __launch_bounds__(256, 2)
void k_gemm_bt(const unsigned short* __restrict__ A, const unsigned short* __restrict__ Bt,
               void* __restrict__ Cout, int N, int K, int Mreal,
               long aBatch, long bBatch, long cBatch, const float* __restrict__ bias){
  __shared__ unsigned short As[128 * 32];
  __shared__ unsigned short Bs[128 * 32];
  const int tid = threadIdx.x, lane = tid & 63, wid = tid >> 6;
  const int wm = wid >> 1, wn = wid & 1;
  const int bm0 = blockIdx.y * 128, bn0 = blockIdx.x * 128;
  A  += (long)blockIdx.z * aBatch;
  Bt += (long)blockIdx.z * bBatch;

  f32x4 acc[4][4];
#pragma unroll
  for (int i = 0; i < 4; ++i)
#pragma unroll
    for (int jx = 0; jx < 4; ++jx) acc[i][jx] = f32x4{0.f, 0.f, 0.f, 0.f};

  for (int k0 = 0; k0 < K; k0 += 32){
    __syncthreads();
#pragma unroll
    for (int cc = 0; cc < 2; ++cc){
      int e = tid + cc * 256;               // 0..511 : 16B segment index
      int row = e >> 2, seg = e & 3;
      const unsigned short* ga = A + ((long)(bm0 + row)) * K + k0 + seg * 8;
      gload16(ga, (char*)As + cc * 4096 + wid * 1024);
      const unsigned short* gb = Bt + ((long)(bn0 + row)) * K + k0 + seg * 8;
      gload16(gb, (char*)Bs + cc * 4096 + wid * 1024);
    }
    __syncthreads();
    s16x8 af[4], bfr[4];
#pragma unroll
    for (int mt = 0; mt < 4; ++mt){
      int arow = wm * 64 + mt * 16 + (lane & 15);
      af[mt] = *(const s16x8*)((const char*)As + arow * 64 + (lane >> 4) * 16);
    }
#pragma unroll
    for (int nt = 0; nt < 4; ++nt){
      int brow = wn * 64 + nt * 16 + (lane & 15);
      bfr[nt] = *(const s16x8*)((const char*)Bs + brow * 64 + (lane >> 4) * 16);
    }
#pragma unroll
    for (int mt = 0; mt < 4; ++mt)
#pragma unroll
      for (int nt = 0; nt < 4; ++nt)
        acc[mt][nt] = __builtin_amdgcn_mfma_f32_16x16x32_bf16(af[mt], bfr[nt], acc[mt][nt], 0, 0, 0);
  }

  long co = (long)blockIdx.z * cBatch;
#pragma unroll
  for (int mt = 0; mt < 4; ++mt){
#pragma unroll
    for (int r = 0; r < 4; ++r){
      int row = bm0 + wm * 64 + mt * 16 + (lane >> 4) * 4 + r;
      if (row < Mreal){
#pragma unroll
        for (int nt = 0; nt < 4; ++nt){
          int col = bn0 + wn * 64 + nt * 16 + (lane & 15);
          float v = acc[mt][nt][r];
          long idx = co + (long)row * N + col;
          if constexpr (EPI == 0) ((float*)Cout)[idx] = v;
          else if constexpr (EPI == 1) ((unsigned short*)Cout)[idx] = f2bf(tanh_f(v));
          else if constexpr (EPI == 2) ((unsigned short*)Cout)[idx] = f2bf(v + bias[col]);
          else ((unsigned short*)Cout)[idx] = f2bf(v);
        }
      }
    }
  }
}

// ---------------- persistent bi-LSTM recurrence (barrier-free waves) ----------------
// 32 WGs: wg<16 forward, wg>=16 backward; WG owns dims j0..j0+31, wave w owns 8 dims
// (all 4 gates). L3 data-as-flag handshake (R3-proven): Hb pre-memset to 0xFFFF
// (bf16 NaN, unreachable); producers global_store_short sc0 sc1; each WAVE polls the
// whole 8x512 h(t-1) tile directly into its MFMA A-fragments with 16x
// global_load_dwordx4 sc0 sc1 — the successful poll IS the fragment load. A-rows
// 8-15 duplicate rows 0-7 (lane&7), outputs of those rows unread. Gate exchange is
// same-wave LDS (program order + lgkmcnt, no barrier). ZERO __syncthreads in the
// step loop. Sentinel detect: v_pk_max_u16 tree (any short==0xFFFF <=> max==0xFFFF).
__global__ __launch_bounds__(256, 1)
void k_lstm(const unsigned short* __restrict__ xw_all,
            const float* __restrict__ Whh_f, const float* __restrict__ Whh_b,
            unsigned short* __restrict__ Hb){
  __shared__ float gl[4 * 8 * 33];          // per-wave gate exchange, stride 33
  const int tid = threadIdx.x, lane = tid & 63, wave = tid >> 6;
  const int wg = blockIdx.x;
  const int dir = wg >> 4, w16 = wg & 15;
  const int j0 = w16 * 32;
  const float* Whh = dir ? Whh_b : Whh_f;
  const unsigned short* xw = xw_all + (long)dir * NROW_ * G4_;

  // lane ownership: one (batch, dim) pair per lane
  const int b_own = lane >> 3, jj = lane & 7;
  const int j_own = j0 + wave * 8 + jj;

  // B fragments: wave w covers cols {i,f}x8dims (Bf0) and {g,o}x8dims (Bf1)
  s16x8 Bf0[16], Bf1[16];
  {
    int c = lane & 15;
    int jd = j0 + wave * 8 + (c & 7);
    int kg = (lane >> 4) * 8;
    const float* r0 = Whh + (long)(((c < 8) ? 0 : 512) + jd) * 512;     // i / f rows
    const float* r1 = Whh + (long)(((c < 8) ? 1024 : 1536) + jd) * 512; // g / o rows
#pragma unroll
    for (int kt = 0; kt < 16; ++kt){
      s16x8 v0, v1;
#pragma unroll
      for (int i = 0; i < 8; ++i){
        v0[i] = (short)f2bf(r0[kt * 32 + kg + i]);
        v1[i] = (short)f2bf(r1[kt * 32 + kg + i]);
      }
      Bf0[kt] = v0; Bf1[kt] = v1;
    }
  }

  const int s0 = dir ? (S_ - 1) : 0;
  const long hstep = dir ? -(long)RNN_ : (long)RNN_;       // per-step h-row stride
  const long xstep = dir ? -8L * G4_ : 8L * G4_;

  // xw prefetch pointer (lane-owned gates)
  const unsigned short* xp = xw + ((long)s0 * 8 + b_own) * G4_ + j_own;
  float xwi = bf2f(xp[0]), xwf = bf2f(xp[512]), xwg = bf2f(xp[1024]), xwo = bf2f(xp[1536]);

  // A-fragment poll base: row lane&7 (rows 8-15 duplicate), k-group (lane>>4)*8
  const unsigned short* ab = Hb + ((long)(lane & 7) * S_ + s0) * RNN_ + dir * HD_ + ((lane >> 4) & 3) * 8;
  // h store pointer (lane-owned value)
  unsigned short* hp = Hb + ((long)b_own * S_ + s0) * RNN_ + dir * HD_ + j_own;

  float* glw = gl + wave * (8 * 33);
  const int c0 = lane & 15;
  const int bb = (lane >> 4) * 4;

  float creg = 0.f;

  for (int t = 0; t < S_; ++t){
    float gi, gf, gg, go;
    if (t == 0){
      gi = xwi; gf = xwf; gg = xwg; go = xwo;
    } else {
      uint4 u[16];
      for (;;){
        asm volatile(
          "global_load_dwordx4 %0, %16, off sc0 sc1\n\t"
          "global_load_dwordx4 %1, %16, off offset:64 sc0 sc1\n\t"
          "global_load_dwordx4 %2, %16, off offset:128 sc0 sc1\n\t"
          "global_load_dwordx4 %3, %16, off offset:192 sc0 sc1\n\t"
          "global_load_dwordx4 %4, %16, off offset:256 sc0 sc1\n\t"
          "global_load_dwordx4 %5, %16, off offset:320 sc0 sc1\n\t"
          "global_load_dwordx4 %6, %16, off offset:384 sc0 sc1\n\t"
          "global_load_dwordx4 %7, %16, off offset:448 sc0 sc1\n\t"
          "global_load_dwordx4 %8, %16, off offset:512 sc0 sc1\n\t"
          "global_load_dwordx4 %9, %16, off offset:576 sc0 sc1\n\t"
          "global_load_dwordx4 %10, %16, off offset:640 sc0 sc1\n\t"
          "global_load_dwordx4 %11, %16, off offset:704 sc0 sc1\n\t"
          "global_load_dwordx4 %12, %16, off offset:768 sc0 sc1\n\t"
          "global_load_dwordx4 %13, %16, off offset:832 sc0 sc1\n\t"
          "global_load_dwordx4 %14, %16, off offset:896 sc0 sc1\n\t"
          "global_load_dwordx4 %15, %16, off offset:960 sc0 sc1\n\t"
          "s_waitcnt vmcnt(0)"
          : "=&v"(u[0]), "=&v"(u[1]), "=&v"(u[2]), "=&v"(u[3]),
            "=&v"(u[4]), "=&v"(u[5]), "=&v"(u[6]), "=&v"(u[7]),
            "=&v"(u[8]), "=&v"(u[9]), "=&v"(u[10]), "=&v"(u[11]),
            "=&v"(u[12]), "=&v"(u[13]), "=&v"(u[14]), "=&v"(u[15])
          : "v"(ab) : "memory");
        unsigned m = pmax16(pmax16(pmax16(pmax4(u[0]), pmax4(u[1])), pmax16(pmax4(u[2]), pmax4(u[3]))),
                            pmax16(pmax16(pmax4(u[4]), pmax4(u[5])), pmax16(pmax4(u[6]), pmax4(u[7]))));
        m = pmax16(m, pmax16(pmax16(pmax16(pmax4(u[8]), pmax4(u[9])), pmax16(pmax4(u[10]), pmax4(u[11]))),
                             pmax16(pmax16(pmax4(u[12]), pmax4(u[13])), pmax16(pmax4(u[14]), pmax4(u[15])))));
        unsigned mm = (m & 0xFFFFu) > (m >> 16) ? (m & 0xFFFFu) : (m >> 16);
        if (mm != 0xFFFFu) break;
      }
      // MFMA: 32 per wave, 4 independent chains
      f32x4 a0a = {0.f,0.f,0.f,0.f}, a0b = a0a, a1a = a0a, a1b = a0a;
#pragma unroll
      for (int kt = 0; kt < 16; kt += 2){
        s16x8 f0 = __builtin_bit_cast(s16x8, u[kt]);
        s16x8 f1 = __builtin_bit_cast(s16x8, u[kt + 1]);
        a0a = __builtin_amdgcn_mfma_f32_16x16x32_bf16(f0, Bf0[kt], a0a, 0, 0, 0);
        a1a = __builtin_amdgcn_mfma_f32_16x16x32_bf16(f0, Bf1[kt], a1a, 0, 0, 0);
        a0b = __builtin_amdgcn_mfma_f32_16x16x32_bf16(f1, Bf0[kt + 1], a0b, 0, 0, 0);
        a1b = __builtin_amdgcn_mfma_f32_16x16x32_bf16(f1, Bf1[kt + 1], a1b, 0, 0, 0);
      }
      f32x4 acc0 = a0a + a0b, acc1 = a1a + a1b;
      // same-wave gate exchange (no barrier: program order + lgkmcnt)
      if (lane < 32){
#pragma unroll
        for (int r = 0; r < 4; ++r){
          glw[(bb + r) * 33 + c0] = acc0[r];
          glw[(bb + r) * 33 + 16 + c0] = acc1[r];
        }
      }
      gi = glw[b_own * 33 + jj]      + xwi;
      gf = glw[b_own * 33 + 8 + jj]  + xwf;
      gg = glw[b_own * 33 + 16 + jj] + xwg;
      go = glw[b_own * 33 + 24 + jj] + xwo;
      ab += hstep;
    }
    creg = sigm(gf) * creg + sigm(gi) * tanh_f(gg);
    float hv = sigm(go) * tanh_f(creg);
    unsigned hd = (unsigned)f2bf(hv);
    asm volatile("global_store_short %0, %1, off sc0 sc1"
                 :: "v"(hp), "v"(hd) : "memory");
    hp += hstep;
    if (t + 1 < S_){
      xp += xstep;
      xwi = bf2f(xp[0]); xwf = bf2f(xp[512]);
      xwg = bf2f(xp[1024]); xwo = bf2f(xp[1536]);
    }
  }
}

// ---------------- fused softmax (over s) + logits ----------------
__global__ __launch_bounds__(256)
void k_softmax_logits(float* __restrict__ alpha, const unsigned short* __restrict__ HOt,
                      const float* __restrict__ Ob, float* __restrict__ logits){
  const int lane = threadIdx.x & 63, wv = threadIdx.x >> 6;
  long row = (long)blockIdx.x * 4 + wv;       // row = b*C + c
  float* a = alpha + row * (long)S_;
  const unsigned short* h = HOt + row * (long)S_;
  float v[32];
  float mx = -1e30f;
#pragma unroll
  for (int jj = 0; jj < 8; ++jj){
    f32x4 t = *(const f32x4*)(a + jj * 256 + lane * 4);
#pragma unroll
    for (int r = 0; r < 4; ++r){ v[jj * 4 + r] = t[r]; mx = fmaxf(mx, t[r]); }
  }
#pragma unroll
  for (int o = 32; o > 0; o >>= 1) mx = fmaxf(mx, __shfl_xor(mx, o));
  float sum = 0.f;
#pragma unroll
  for (int i = 0; i < 32; ++i){ v[i] = __expf(v[i] - mx); sum += v[i]; }
#pragma unroll
  for (int o = 32; o > 0; o >>= 1) sum += __shfl_xor(sum, o);
  float inv = 1.f / sum;
  float dot = 0.f;
#pragma unroll
  for (int jj = 0; jj < 8; ++jj){
    s16x4 hv = *(const s16x4*)(h + jj * 256 + lane * 4);
    f32x4 av;
#pragma unroll
    for (int r = 0; r < 4; ++r){
      float al = v[jj * 4 + r] * inv;
      av[r] = al;
      dot += al * bf2f((unsigned short)hv[r]);
    }
    *(f32x4*)(a + jj * 256 + lane * 4) = av;
  }
#pragma unroll
  for (int o = 32; o > 0; o >>= 1) dot += __shfl_xor(dot, o);
  if (lane == 0){
    int c = (int)(row % C_);
    logits[row] = dot + Ob[c];
  }
}

// ---------------- host ----------------
extern "C" void kernel_launch(void* const* d_in, const int* in_sizes, int n_in,
                              void* d_out, int out_size, void* d_ws, size_t ws_size,
                              hipStream_t stream){
  const int*   text  = (const int*)d_in[0];
  const float* emb   = (const float*)d_in[2];
  const float* Wih_f = (const float*)d_in[3];
  const float* Whh_f = (const float*)d_in[4];
  const float* b_f   = (const float*)d_in[5];
  const float* Wih_b = (const float*)d_in[6];
  const float* Whh_b = (const float*)d_in[7];
  const float* b_b   = (const float*)d_in[8];
  const float* Ww    = (const float*)d_in[9];
  const float* Qw    = (const float*)d_in[10];
  const float* Ow    = (const float*)d_in[11];
  const float* Ob    = (const float*)d_in[12];

  char* ws = (char*)d_ws;
  long o = 0;
  unsigned short* wWihF = (unsigned short*)(ws + o); o += 2048L * 320 * 2;
  unsigned short* wWihB = (unsigned short*)(ws + o); o += 2048L * 320 * 2;
  unsigned short* wWw   = (unsigned short*)(ws + o); o += 512L * 1024 * 2;
  unsigned short* wQw   = (unsigned short*)(ws + o); o += 8960L * 512 * 2;
  unsigned short* wOw   = (unsigned short*)(ws + o); o += 8960L * 1024 * 2;
  unsigned short* wH    = (unsigned short*)(ws + o); o += 8L * 2048 * 1024 * 2;
  unsigned short* wZ    = (unsigned short*)(ws + o); o += 16384L * 512 * 2;
  char* regA = ws + o;                                // reused region
  unsigned short* wXe  = (unsigned short*)regA;                         // [16384][320]
  unsigned short* wXw  = (unsigned short*)(regA + 16384L * 320 * 2);    // [2][16384][2048]
  unsigned short* wHOt = (unsigned short*)regA;                         // [8][8921][2048] (after LSTM)

  float* logits = (float*)d_out;
  float* alpha  = logits + 8L * C_;    // [8][8921][2048], also holds raw scores

  // re-arm the data-as-flag sentinel every launch (graph-replay safe)
  hipMemsetAsync(wH, 0xFF, 8L * 2048 * 1024 * 2, stream);
  k_cvt_pad<<<2048, 256, 0, stream>>>(Wih_f, wWihF, 2048, 300, 320);
  k_cvt_pad<<<2048, 256, 0, stream>>>(Wih_b, wWihB, 2048, 300, 320);
  k_cvt_pad<<<512,  256, 0, stream>>>(Ww, wWw, 512, 1024, 1024);
  k_cvt_pad<<<8960, 256, 0, stream>>>(Qw, wQw, 8921, 512, 512);
  k_cvt_pad<<<8960, 256, 0, stream>>>(Ow, wOw, 8921, 1024, 1024);
  k_embed<<<16384, 256, 0, stream>>>(text, emb, wXe);

  // xw[dir] = xe @ Wih^T + b  -> bf16 [16384][2048]
  k_gemm_bt<2><<<dim3(16, 128, 1), 256, 0, stream>>>(wXe, wWihF, wXw, 2048, 320, 16384, 0, 0, 0, b_f);
  k_gemm_bt<2><<<dim3(16, 128, 1), 256, 0, stream>>>(wXe, wWihB, wXw + 16384L * 2048, 2048, 320, 16384, 0, 0, 0, b_b);

  k_lstm<<<32, 256, 0, stream>>>(wXw, Whh_f, Whh_b, wH);

  // Z = tanh(H @ Ww^T)  [16384][512] bf16
  k_gemm_bt<1><<<dim3(4, 128, 1), 256, 0, stream>>>(wH, wWw, wZ, 512, 1024, 16384, 0, 0, 0, nullptr);
  // scores[b] = Qw @ Z[b]^T  -> fp32 into alpha region
  k_gemm_bt<0><<<dim3(16, 70, 8), 256, 0, stream>>>(wQw, wZ, alpha, 2048, 512, C_, 0, 2048L * 512, (long)C_ * 2048, nullptr);
  // HOt[b] = Ow @ H[b]^T  -> bf16
  k_gemm_bt<3><<<dim3(16, 70, 8), 256, 0, stream>>>(wOw, wH, wHOt, 2048, 1024, C_, 0, 2048L * 1024, (long)C_ * 2048, nullptr);

  k_softmax_logits<<<17842, 256, 0, stream>>>(alpha, wHOt, Ob, logits);
}

// Round 7
// 4998.339 us; speedup vs baseline: 1.8993x; 1.8993x over previous
//
#include <hip/hip_runtime.h>
#include <hip/hip_bf16.h>

typedef __attribute__((ext_vector_type(4))) float f32x4;
typedef __attribute__((ext_vector_type(8))) short s16x8;
typedef __attribute__((ext_vector_type(4))) short s16x4;

#define DI __device__ __forceinline__

static constexpr int B_ = 8, S_ = 2048, E_ = 300, EP_ = 320, HD_ = 512, G4_ = 2048;
static constexpr int C_ = 8921, RNN_ = 1024, NROW_ = 16384;

DI float bf2f(unsigned short u){ unsigned int x = ((unsigned int)u) << 16; return __builtin_bit_cast(float, x); }
DI unsigned short f2bf(float f){
  unsigned int x = __builtin_bit_cast(unsigned int, f);
  x += 0x7fff + ((x >> 16) & 1);
  return (unsigned short)(x >> 16);
}
DI float sigm(float x){ return 1.f / (1.f + __expf(-x)); }
DI float tanh_f(float x){
  x = fminf(fmaxf(x, -15.f), 15.f);
  float e = __expf(2.f * x);
  return (e - 1.f) / (e + 1.f);
}
DI void gload16(const void* g, void* l){
  __builtin_amdgcn_global_load_lds((const __attribute__((address_space(1))) void*)g,
                                   (__attribute__((address_space(3))) void*)l, 16, 0, 0);
}
DI unsigned has_sent(unsigned x){   // any bf16 half == 0xFFFF (sentinel NaN)?
  return (unsigned)(((x & 0xFFFFu) == 0xFFFFu) | ((x >> 16) == 0xFFFFu));
}

// ---------------- convert / pad fp32 -> bf16 ----------------
__global__ void k_cvt_pad(const float* __restrict__ src, unsigned short* __restrict__ dst,
                          int Rs, int Cs, int Cd){
  int r = blockIdx.x;
  long db = (long)r * Cd;
  for (int c = threadIdx.x; c < Cd; c += blockDim.x){
    float v = (r < Rs && c < Cs) ? src[(long)r * Cs + c] : 0.f;
    dst[db + c] = f2bf(v);
  }
}

// ---------------- embedding gather -> xe [S][B][EP] bf16 ----------------
__global__ void k_embed(const int* __restrict__ text, const float* __restrict__ emb,
                        unsigned short* __restrict__ xe){
  int m = blockIdx.x;            // m = s*8 + b
  int s = m >> 3, b = m & 7;
  int tok = text[b * S_ + s];
  const float* e = emb + (long)tok * E_;
  long db = (long)m * EP_;
  for (int c = threadIdx.x; c < EP_; c += blockDim.x){
    float v = (c < E_) ? e[c] : 0.f;
    xe[db + c] = f2bf(v);
  }
}

// ---------------- gemm_bt: C[M,N] = A[M,K] * Bt[N,K]^T  (bf16 in, fp32 acc) --------
// EPI: 0 = fp32 store, 1 = bf16 tanh, 2 = bf16 + bias, 3 = bf16
template<int EPI>
__global__ __launch_bounds__(256, 2)
void k_gemm_bt(const unsigned short* __restrict__ A, const unsigned short* __restrict__ Bt,
               void* __restrict__ Cout, int N, int K, int Mreal,
               long aBatch, long bBatch, long cBatch, const float* __restrict__ bias){
  __shared__ unsigned short As[128 * 32];
  __shared__ unsigned short Bs[128 * 32];
  const int tid = threadIdx.x, lane = tid & 63, wid = tid >> 6;
  const int wm = wid >> 1, wn = wid & 1;
  const int bm0 = blockIdx.y * 128, bn0 = blockIdx.x * 128;
  A  += (long)blockIdx.z * aBatch;
  Bt += (long)blockIdx.z * bBatch;

  f32x4 acc[4][4];
#pragma unroll
  for (int i = 0; i < 4; ++i)
#pragma unroll
    for (int jx = 0; jx < 4; ++jx) acc[i][jx] = f32x4{0.f, 0.f, 0.f, 0.f};

  for (int k0 = 0; k0 < K; k0 += 32){
    __syncthreads();
#pragma unroll
    for (int cc = 0; cc < 2; ++cc){
      int e = tid + cc * 256;               // 0..511 : 16B segment index
      int row = e >> 2, seg = e & 3;
      const unsigned short* ga = A + ((long)(bm0 + row)) * K + k0 + seg * 8;
      gload16(ga, (char*)As + cc * 4096 + wid * 1024);
      const unsigned short* gb = Bt + ((long)(bn0 + row)) * K + k0 + seg * 8;
      gload16(gb, (char*)Bs + cc * 4096 + wid * 1024);
    }
    __syncthreads();
    s16x8 af[4], bfr[4];
#pragma unroll
    for (int mt = 0; mt < 4; ++mt){
      int arow = wm * 64 + mt * 16 + (lane & 15);
      af[mt] = *(const s16x8*)((const char*)As + arow * 64 + (lane >> 4) * 16);
    }
#pragma unroll
    for (int nt = 0; nt < 4; ++nt){
      int brow = wn * 64 + nt * 16 + (lane & 15);
      bfr[nt] = *(const s16x8*)((const char*)Bs + brow * 64 + (lane >> 4) * 16);
    }
#pragma unroll
    for (int mt = 0; mt < 4; ++mt)
#pragma unroll
      for (int nt = 0; nt < 4; ++nt)
        acc[mt][nt] = __builtin_amdgcn_mfma_f32_16x16x32_bf16(af[mt], bfr[nt], acc[mt][nt], 0, 0, 0);
  }

  long co = (long)blockIdx.z * cBatch;
#pragma unroll
  for (int mt = 0; mt < 4; ++mt){
#pragma unroll
    for (int r = 0; r < 4; ++r){
      int row = bm0 + wm * 64 + mt * 16 + (lane >> 4) * 4 + r;
      if (row < Mreal){
#pragma unroll
        for (int nt = 0; nt < 4; ++nt){
          int col = bn0 + wn * 64 + nt * 16 + (lane & 15);
          float v = acc[mt][nt][r];
          long idx = co + (long)row * N + col;
          if constexpr (EPI == 0) ((float*)Cout)[idx] = v;
          else if constexpr (EPI == 1) ((unsigned short*)Cout)[idx] = f2bf(tanh_f(v));
          else if constexpr (EPI == 2) ((unsigned short*)Cout)[idx] = f2bf(v + bias[col]);
          else ((unsigned short*)Cout)[idx] = f2bf(v);
        }
      }
    }
  }
}

// ---------------- persistent bi-LSTM recurrence ----------------
// R3 cooperative structure + R6 same-wave gate exchange.
// 32 WGs: wg<16 forward, wg>=16 backward. WG owns 32 h-dims; wave w owns 8 dims
// (ALL 4 gates i,f,g,o -> gate exchange is same-wave LDS, no barrier).
// Cross-WG handshake: DATA-AS-FLAG via L3 (proven R3). Hb pre-memset to 0xFFFF
// (bf16 NaN, unreachable); producers global_store_short sc0 sc1 (no ack wait);
// consumers cooperatively poll their own 2x16B chunks with sc0 sc1 loads — the
// successful poll IS the staging load. Each wave's poll spans 2 full batch rows
// (all 512 dims), so no wave passes the poll until every producer wave (incl. its
// own WG's) has stored step t-1 -> the poll guards hA reuse; the single barrier
// covers cross-wave staging visibility. ONE __syncthreads per step.
__global__ __launch_bounds__(256, 1)
void k_lstm(const unsigned short* __restrict__ xw_all,
            const float* __restrict__ Whh_f, const float* __restrict__ Whh_b,
            unsigned short* __restrict__ Hb){
  __shared__ unsigned short hA[16 * 512];   // A tile [16 rows=batch][512 k], swizzled
  __shared__ float gl[4 * 8 * 33];          // per-wave gate exchange, stride 33
  char* hAc = (char*)hA;
  const int tid = threadIdx.x, lane = tid & 63, wave = tid >> 6;
  const int wg = blockIdx.x;
  const int dir = wg >> 4, w16 = wg & 15;
  const int j0 = w16 * 32;
  const float* Whh = dir ? Whh_b : Whh_f;
  const unsigned short* xw = xw_all + (long)dir * NROW_ * G4_;

  // lane ownership: one (batch, dim) pair per lane; wave owns 8 dims x 4 gates
  const int b_own = lane >> 3, jj = lane & 7;
  const int j_own = j0 + wave * 8 + jj;

  // B fragments (R6 layout): cols 0-7 = gate i (dims jj), 8-15 = f  -> Bf0
  //                          cols 0-7 = gate g,           8-15 = o  -> Bf1
  s16x8 Bf0[16], Bf1[16];
  {
    int c = lane & 15;
    int jd = j0 + wave * 8 + (c & 7);
    int kg = (lane >> 4) * 8;
    const float* r0 = Whh + (long)(((c < 8) ? 0 : 512) + jd) * 512;     // i / f rows
    const float* r1 = Whh + (long)(((c < 8) ? 1024 : 1536) + jd) * 512; // g / o rows
#pragma unroll
    for (int kt = 0; kt < 16; ++kt){
      s16x8 v0, v1;
#pragma unroll
      for (int i = 0; i < 8; ++i){
        v0[i] = (short)f2bf(r0[kt * 32 + kg + i]);
        v1[i] = (short)f2bf(r1[kt * 32 + kg + i]);
      }
      Bf0[kt] = v0; Bf1[kt] = v1;
    }
  }
  for (int i = tid; i < 16 * 512; i += 256) hA[i] = 0;

  const int s0 = dir ? (S_ - 1) : 0;

  float creg = 0.f;
  float xwi, xwf, xwg, xwo;
  {
    long base = ((long)s0 * 8 + b_own) * G4_ + j_own;
    xwi = bf2f(xw[base]); xwf = bf2f(xw[base + 512]);
    xwg = bf2f(xw[base + 1024]); xwo = bf2f(xw[base + 1536]);
  }
  // this thread's two 16B staging chunks of the h(t-1) tile (rows bp0, bp0+4)
  const int bp0 = tid >> 6, seg0 = tid & 63;
  const int lds0 = (bp0 * 1024 + seg0 * 16) ^ ((bp0 & 7) << 4);
  const int lds1 = ((bp0 + 4) * 1024 + seg0 * 16) ^ (((bp0 + 4) & 7) << 4);

  float* glw = gl + wave * (8 * 33);
  const int c0 = lane & 15;
  const int bb = (lane >> 4) * 4;
  __syncthreads();

  for (int t = 0; t < S_; ++t){
    int s = dir ? (S_ - 1 - t) : t;
    float gi, gf, gg, go;
    if (t == 0){
      gi = xwi; gf = xwf; gg = xwg; go = xwo;
    } else {
      int sp = dir ? (s + 1) : (s - 1);
      const uint4* gp0 = (const uint4*)(Hb + ((long)bp0 * S_ + sp) * RNN_ + dir * HD_) + seg0;
      const uint4* gp1 = (const uint4*)(Hb + ((long)(bp0 + 4) * S_ + sp) * RNN_ + dir * HD_) + seg0;
      uint4 va0, va1;
      for (;;){
        asm volatile("global_load_dwordx4 %0, %2, off sc0 sc1\n\t"
                     "global_load_dwordx4 %1, %3, off sc0 sc1\n\t"
                     "s_waitcnt vmcnt(0)"
                     : "=&v"(va0), "=&v"(va1) : "v"(gp0), "v"(gp1) : "memory");
        unsigned bad = has_sent(va0.x) | has_sent(va0.y) | has_sent(va0.z) | has_sent(va0.w)
                     | has_sent(va1.x) | has_sent(va1.y) | has_sent(va1.z) | has_sent(va1.w);
        if (!bad) break;
      }
      __builtin_amdgcn_sched_barrier(0);
      *(uint4*)(hAc + lds0) = va0;
      *(uint4*)(hAc + lds1) = va1;
      __syncthreads();

      // gates: [16(batch,pad)][16 cols] per wave; 4 chains of 8 MFMA
      f32x4 a0a = {0.f,0.f,0.f,0.f}, a0b = a0a, a1a = a0a, a1b = a0a;
      {
        int arow = lane & 15;
        int sw = (arow & 7) << 4;
        int kg16 = (lane >> 4) * 16;
#pragma unroll
        for (int kt = 0; kt < 16; kt += 2){
          int ab0 = (arow * 1024 + kt * 64 + kg16) ^ sw;
          int ab1 = (arow * 1024 + (kt + 1) * 64 + kg16) ^ sw;
          s16x8 afr0 = *(const s16x8*)(hAc + ab0);
          s16x8 afr1 = *(const s16x8*)(hAc + ab1);
          a0a = __builtin_amdgcn_mfma_f32_16x16x32_bf16(afr0, Bf0[kt], a0a, 0, 0, 0);
          a1a = __builtin_amdgcn_mfma_f32_16x16x32_bf16(afr0, Bf1[kt], a1a, 0, 0, 0);
          a0b = __builtin_amdgcn_mfma_f32_16x16x32_bf16(afr1, Bf0[kt + 1], a0b, 0, 0, 0);
          a1b = __builtin_amdgcn_mfma_f32_16x16x32_bf16(afr1, Bf1[kt + 1], a1b, 0, 0, 0);
        }
      }
      f32x4 acc0 = a0a + a0b, acc1 = a1a + a1b;
      // same-wave gate exchange (program order + lgkmcnt, no barrier)
      if (lane < 32){
#pragma unroll
        for (int r = 0; r < 4; ++r){
          glw[(bb + r) * 33 + c0] = acc0[r];
          glw[(bb + r) * 33 + 16 + c0] = acc1[r];
        }
      }
      gi = glw[b_own * 33 + jj]      + xwi;
      gf = glw[b_own * 33 + 8 + jj]  + xwf;
      gg = glw[b_own * 33 + 16 + jj] + xwg;
      go = glw[b_own * 33 + 24 + jj] + xwo;
    }
    creg = sigm(gf) * creg + sigm(gi) * tanh_f(gg);
    float hv = sigm(go) * tanh_f(creg);
    unsigned short* hp = Hb + ((long)b_own * S_ + s) * RNN_ + dir * HD_ + j_own;
    unsigned hd = (unsigned)f2bf(hv);
    asm volatile("global_store_short %0, %1, off sc0 sc1"
                 :: "v"(hp), "v"(hd) : "memory");
    if (t + 1 < S_){
      int sn = dir ? (s - 1) : (s + 1);
      long base = ((long)sn * 8 + b_own) * G4_ + j_own;
      xwi = bf2f(xw[base]); xwf = bf2f(xw[base + 512]);
      xwg = bf2f(xw[base + 1024]); xwo = bf2f(xw[base + 1536]);
    }
  }
}

// ---------------- fused softmax (over s) + logits ----------------
__global__ __launch_bounds__(256)
void k_softmax_logits(float* __restrict__ alpha, const unsigned short* __restrict__ HOt,
                      const float* __restrict__ Ob, float* __restrict__ logits){
  const int lane = threadIdx.x & 63, wv = threadIdx.x >> 6;
  long row = (long)blockIdx.x * 4 + wv;       // row = b*C + c
  float* a = alpha + row * (long)S_;
  const unsigned short* h = HOt + row * (long)S_;
  float v[32];
  float mx = -1e30f;
#pragma unroll
  for (int jj = 0; jj < 8; ++jj){
    f32x4 t = *(const f32x4*)(a + jj * 256 + lane * 4);
#pragma unroll
    for (int r = 0; r < 4; ++r){ v[jj * 4 + r] = t[r]; mx = fmaxf(mx, t[r]); }
  }
#pragma unroll
  for (int o = 32; o > 0; o >>= 1) mx = fmaxf(mx, __shfl_xor(mx, o));
  float sum = 0.f;
#pragma unroll
  for (int i = 0; i < 32; ++i){ v[i] = __expf(v[i] - mx); sum += v[i]; }
#pragma unroll
  for (int o = 32; o > 0; o >>= 1) sum += __shfl_xor(sum, o);
  float inv = 1.f / sum;
  float dot = 0.f;
#pragma unroll
  for (int jj = 0; jj < 8; ++jj){
    s16x4 hv = *(const s16x4*)(h + jj * 256 + lane * 4);
    f32x4 av;
#pragma unroll
    for (int r = 0; r < 4; ++r){
      float al = v[jj * 4 + r] * inv;
      av[r] = al;
      dot += al * bf2f((unsigned short)hv[r]);
    }
    *(f32x4*)(a + jj * 256 + lane * 4) = av;
  }
#pragma unroll
  for (int o = 32; o > 0; o >>= 1) dot += __shfl_xor(dot, o);
  if (lane == 0){
    int c = (int)(row % C_);
    logits[row] = dot + Ob[c];
  }
}

// ---------------- host ----------------
extern "C" void kernel_launch(void* const* d_in, const int* in_sizes, int n_in,
                              void* d_out, int out_size, void* d_ws, size_t ws_size,
                              hipStream_t stream){
  const int*   text  = (const int*)d_in[0];
  const float* emb   = (const float*)d_in[2];
  const float* Wih_f = (const float*)d_in[3];
  const float* Whh_f = (const float*)d_in[4];
  const float* b_f   = (const float*)d_in[5];
  const float* Wih_b = (const float*)d_in[6];
  const float* Whh_b = (const float*)d_in[7];
  const float* b_b   = (const float*)d_in[8];
  const float* Ww    = (const float*)d_in[9];
  const float* Qw    = (const float*)d_in[10];
  const float* Ow    = (const float*)d_in[11];
  const float* Ob    = (const float*)d_in[12];

  char* ws = (char*)d_ws;
  long o = 0;
  unsigned short* wWihF = (unsigned short*)(ws + o); o += 2048L * 320 * 2;
  unsigned short* wWihB = (unsigned short*)(ws + o); o += 2048L * 320 * 2;
  unsigned short* wWw   = (unsigned short*)(ws + o); o += 512L * 1024 * 2;
  unsigned short* wQw   = (unsigned short*)(ws + o); o += 8960L * 512 * 2;
  unsigned short* wOw   = (unsigned short*)(ws + o); o += 8960L * 1024 * 2;
  unsigned short* wH    = (unsigned short*)(ws + o); o += 8L * 2048 * 1024 * 2;
  unsigned short* wZ    = (unsigned short*)(ws + o); o += 16384L * 512 * 2;
  char* regA = ws + o;                                // reused region
  unsigned short* wXe  = (unsigned short*)regA;                         // [16384][320]
  unsigned short* wXw  = (unsigned short*)(regA + 16384L * 320 * 2);    // [2][16384][2048]
  unsigned short* wHOt = (unsigned short*)regA;                         // [8][8921][2048] (after LSTM)

  float* logits = (float*)d_out;
  float* alpha  = logits + 8L * C_;    // [8][8921][2048], also holds raw scores

  // re-arm the data-as-flag sentinel every launch (graph-replay safe)
  hipMemsetAsync(wH, 0xFF, 8L * 2048 * 1024 * 2, stream);
  k_cvt_pad<<<2048, 256, 0, stream>>>(Wih_f, wWihF, 2048, 300, 320);
  k_cvt_pad<<<2048, 256, 0, stream>>>(Wih_b, wWihB, 2048, 300, 320);
  k_cvt_pad<<<512,  256, 0, stream>>>(Ww, wWw, 512, 1024, 1024);
  k_cvt_pad<<<8960, 256, 0, stream>>>(Qw, wQw, 8921, 512, 512);
  k_cvt_pad<<<8960, 256, 0, stream>>>(Ow, wOw, 8921, 1024, 1024);
  k_embed<<<16384, 256, 0, stream>>>(text, emb, wXe);

  // xw[dir] = xe @ Wih^T + b  -> bf16 [16384][2048]
  k_gemm_bt<2><<<dim3(16, 128, 1), 256, 0, stream>>>(wXe, wWihF, wXw, 2048, 320, 16384, 0, 0, 0, b_f);
  k_gemm_bt<2><<<dim3(16, 128, 1), 256, 0, stream>>>(wXe, wWihB, wXw + 16384L * 2048, 2048, 320, 16384, 0, 0, 0, b_b);

  k_lstm<<<32, 256, 0, stream>>>(wXw, Whh_f, Whh_b, wH);

  // Z = tanh(H @ Ww^T)  [16384][512] bf16
  k_gemm_bt<1><<<dim3(4, 128, 1), 256, 0, stream>>>(wH, wWw, wZ, 512, 1024, 16384, 0, 0, 0, nullptr);
  // scores[b] = Qw @ Z[b]^T  -> fp32 into alpha region
  k_gemm_bt<0><<<dim3(16, 70, 8), 256, 0, stream>>>(wQw, wZ, alpha, 2048, 512, C_, 0, 2048L * 512, (long)C_ * 2048, nullptr);
  // HOt[b] = Ow @ H[b]^T  -> bf16
  k_gemm_bt<3><<<dim3(16, 70, 8), 256, 0, stream>>>(wOw, wH, wHOt, 2048, 1024, C_, 0, 2048L * 1024, (long)C_ * 2048, nullptr);

  k_softmax_logits<<<17842, 256, 0, stream>>>(alpha, wHOt, Ob, logits);
}

// Round 8
// 4998.012 us; speedup vs baseline: 1.8994x; 1.0001x over previous
//
#include <hip/hip_runtime.h>
#include <hip/hip_bf16.h>

typedef __attribute__((ext_vector_type(4))) float f32x4;
typedef __attribute__((ext_vector_type(8))) short s16x8;
typedef __attribute__((ext_vector_type(4))) short s16x4;

#define DI __device__ __forceinline__

static constexpr int B_ = 8, S_ = 2048, E_ = 300, EP_ = 320, HD_ = 512, G4_ = 2048;
static constexpr int C_ = 8921, RNN_ = 1024, NROW_ = 16384;

DI float bf2f(unsigned short u){ unsigned int x = ((unsigned int)u) << 16; return __builtin_bit_cast(float, x); }
DI unsigned short f2bf(float f){
  unsigned int x = __builtin_bit_cast(unsigned int, f);
  x += 0x7fff + ((x >> 16) & 1);
  return (unsigned short)(x >> 16);
}
DI float sigm(float x){ return 1.f / (1.f + __expf(-x)); }
DI float tanh_f(float x){
  x = fminf(fmaxf(x, -15.f), 15.f);
  float e = __expf(2.f * x);
  return (e - 1.f) / (e + 1.f);
}
DI void gload16(const void* g, void* l){
  __builtin_amdgcn_global_load_lds((const __attribute__((address_space(1))) void*)g,
                                   (__attribute__((address_space(3))) void*)l, 16, 0, 0);
}
DI unsigned has_sent(unsigned x){   // any bf16 half == 0xFFFF (sentinel NaN)?
  return (unsigned)(((x & 0xFFFFu) == 0xFFFFu) | ((x >> 16) == 0xFFFFu));
}

// ---------------- convert / pad fp32 -> bf16 ----------------
__global__ void k_cvt_pad(const float* __restrict__ src, unsigned short* __restrict__ dst,
                          int Rs, int Cs, int Cd){
  int r = blockIdx.x;
  long db = (long)r * Cd;
  for (int c = threadIdx.x; c < Cd; c += blockDim.x){
    float v = (r < Rs && c < Cs) ? src[(long)r * Cs + c] : 0.f;
    dst[db + c] = f2bf(v);
  }
}

// ---------------- embedding gather -> xe [S][B][EP] bf16 ----------------
__global__ void k_embed(const int* __restrict__ text, const float* __restrict__ emb,
                        unsigned short* __restrict__ xe){
  int m = blockIdx.x;            // m = s*8 + b
  int s = m >> 3, b = m & 7;
  int tok = text[b * S_ + s];
  const float* e = emb + (long)tok * E_;
  long db = (long)m * EP_;
  for (int c = threadIdx.x; c < EP_; c += blockDim.x){
    float v = (c < E_) ? e[c] : 0.f;
    xe[db + c] = f2bf(v);
  }
}

// ---------------- gemm_bt: C[M,N] = A[M,K] * Bt[N,K]^T  (bf16 in, fp32 acc) --------
// EPI: 0 = fp32 store, 1 = bf16 tanh, 2 = bf16 + bias, 3 = bf16
template<int EPI>
__global__ __launch_bounds__(256, 2)
void k_gemm_bt(const unsigned short* __restrict__ A, const unsigned short* __restrict__ Bt,
               void* __restrict__ Cout, int N, int K, int Mreal,
               long aBatch, long bBatch, long cBatch, const float* __restrict__ bias){
  __shared__ unsigned short As[128 * 32];
  __shared__ unsigned short Bs[128 * 32];
  const int tid = threadIdx.x, lane = tid & 63, wid = tid >> 6;
  const int wm = wid >> 1, wn = wid & 1;
  const int bm0 = blockIdx.y * 128, bn0 = blockIdx.x * 128;
  A  += (long)blockIdx.z * aBatch;
  Bt += (long)blockIdx.z * bBatch;

  f32x4 acc[4][4];
#pragma unroll
  for (int i = 0; i < 4; ++i)
#pragma unroll
    for (int jx = 0; jx < 4; ++jx) acc[i][jx] = f32x4{0.f, 0.f, 0.f, 0.f};

  for (int k0 = 0; k0 < K; k0 += 32){
    __syncthreads();
#pragma unroll
    for (int cc = 0; cc < 2; ++cc){
      int e = tid + cc * 256;               // 0..511 : 16B segment index
      int row = e >> 2, seg = e & 3;
      const unsigned short* ga = A + ((long)(bm0 + row)) * K + k0 + seg * 8;
      gload16(ga, (char*)As + cc * 4096 + wid * 1024);
      const unsigned short* gb = Bt + ((long)(bn0 + row)) * K + k0 + seg * 8;
      gload16(gb, (char*)Bs + cc * 4096 + wid * 1024);
    }
    __syncthreads();
    s16x8 af[4], bfr[4];
#pragma unroll
    for (int mt = 0; mt < 4; ++mt){
      int arow = wm * 64 + mt * 16 + (lane & 15);
      af[mt] = *(const s16x8*)((const char*)As + arow * 64 + (lane >> 4) * 16);
    }
#pragma unroll
    for (int nt = 0; nt < 4; ++nt){
      int brow = wn * 64 + nt * 16 + (lane & 15);
      bfr[nt] = *(const s16x8*)((const char*)Bs + brow * 64 + (lane >> 4) * 16);
    }
#pragma unroll
    for (int mt = 0; mt < 4; ++mt)
#pragma unroll
      for (int nt = 0; nt < 4; ++nt)
        acc[mt][nt] = __builtin_amdgcn_mfma_f32_16x16x32_bf16(af[mt], bfr[nt], acc[mt][nt], 0, 0, 0);
  }

  long co = (long)blockIdx.z * cBatch;
#pragma unroll
  for (int mt = 0; mt < 4; ++mt){
#pragma unroll
    for (int r = 0; r < 4; ++r){
      int row = bm0 + wm * 64 + mt * 16 + (lane >> 4) * 4 + r;
      if (row < Mreal){
#pragma unroll
        for (int nt = 0; nt < 4; ++nt){
          int col = bn0 + wn * 64 + nt * 16 + (lane & 15);
          float v = acc[mt][nt][r];
          long idx = co + (long)row * N + col;
          if constexpr (EPI == 0) ((float*)Cout)[idx] = v;
          else if constexpr (EPI == 1) ((unsigned short*)Cout)[idx] = f2bf(tanh_f(v));
          else if constexpr (EPI == 2) ((unsigned short*)Cout)[idx] = f2bf(v + bias[col]);
          else ((unsigned short*)Cout)[idx] = f2bf(v);
        }
      }
    }
  }
}

// ---------------- persistent bi-LSTM recurrence ----------------
// R7 structure with compute-side trims: stride-40 conflict-free gate exchange,
// 8 independent MFMA chains of 4. Handshake unchanged (L3 data-as-flag, R3-proven).
__global__ __launch_bounds__(256, 1)
void k_lstm(const unsigned short* __restrict__ xw_all,
            const float* __restrict__ Whh_f, const float* __restrict__ Whh_b,
            unsigned short* __restrict__ Hb){
  __shared__ unsigned short hA[16 * 512];   // A tile [16 rows=batch][512 k], swizzled
  __shared__ float gl[4 * 8 * 40];          // per-wave gate exchange: [b*40 + gate*10 + jj]
  char* hAc = (char*)hA;
  const int tid = threadIdx.x, lane = tid & 63, wave = tid >> 6;
  const int wg = blockIdx.x;
  const int dir = wg >> 4, w16 = wg & 15;
  const int j0 = w16 * 32;
  const float* Whh = dir ? Whh_b : Whh_f;
  const unsigned short* xw = xw_all + (long)dir * NROW_ * G4_;

  // lane ownership: one (batch, dim) pair per lane; wave owns 8 dims x 4 gates
  const int b_own = lane >> 3, jj = lane & 7;
  const int j_own = j0 + wave * 8 + jj;

  // B fragments: cols 0-7 = gate i (dims jj), 8-15 = f -> Bf0 ; g/o -> Bf1
  s16x8 Bf0[16], Bf1[16];
  {
    int c = lane & 15;
    int jd = j0 + wave * 8 + (c & 7);
    int kg = (lane >> 4) * 8;
    const float* r0 = Whh + (long)(((c < 8) ? 0 : 512) + jd) * 512;     // i / f rows
    const float* r1 = Whh + (long)(((c < 8) ? 1024 : 1536) + jd) * 512; // g / o rows
#pragma unroll
    for (int kt = 0; kt < 16; ++kt){
      s16x8 v0, v1;
#pragma unroll
      for (int i = 0; i < 8; ++i){
        v0[i] = (short)f2bf(r0[kt * 32 + kg + i]);
        v1[i] = (short)f2bf(r1[kt * 32 + kg + i]);
      }
      Bf0[kt] = v0; Bf1[kt] = v1;
    }
  }
  for (int i = tid; i < 16 * 512; i += 256) hA[i] = 0;

  const int s0 = dir ? (S_ - 1) : 0;

  float creg = 0.f;
  float xwi, xwf, xwg, xwo;
  {
    long base = ((long)s0 * 8 + b_own) * G4_ + j_own;
    xwi = bf2f(xw[base]); xwf = bf2f(xw[base + 512]);
    xwg = bf2f(xw[base + 1024]); xwo = bf2f(xw[base + 1536]);
  }
  // this thread's two 16B staging chunks of the h(t-1) tile (rows bp0, bp0+4)
  const int bp0 = tid >> 6, seg0 = tid & 63;
  const int lds0 = (bp0 * 1024 + seg0 * 16) ^ ((bp0 & 7) << 4);
  const int lds1 = ((bp0 + 4) * 1024 + seg0 * 16) ^ (((bp0 + 4) & 7) << 4);

  float* glw = gl + wave * (8 * 40);
  const int c0 = lane & 15;
  const int bb = (lane >> 4) * 4;
  const int woff = (c0 >> 3) * 10 + (c0 & 7);   // gate-column offset within i/f or g/o pair
  __syncthreads();

  for (int t = 0; t < S_; ++t){
    int s = dir ? (S_ - 1 - t) : t;
    float gi, gf, gg, go;
    if (t == 0){
      gi = xwi; gf = xwf; gg = xwg; go = xwo;
    } else {
      int sp = dir ? (s + 1) : (s - 1);
      const uint4* gp0 = (const uint4*)(Hb + ((long)bp0 * S_ + sp) * RNN_ + dir * HD_) + seg0;
      const uint4* gp1 = (const uint4*)(Hb + ((long)(bp0 + 4) * S_ + sp) * RNN_ + dir * HD_) + seg0;
      uint4 va0, va1;
      for (;;){
        asm volatile("global_load_dwordx4 %0, %2, off sc0 sc1\n\t"
                     "global_load_dwordx4 %1, %3, off sc0 sc1\n\t"
                     "s_waitcnt vmcnt(0)"
                     : "=&v"(va0), "=&v"(va1) : "v"(gp0), "v"(gp1) : "memory");
        unsigned bad = has_sent(va0.x) | has_sent(va0.y) | has_sent(va0.z) | has_sent(va0.w)
                     | has_sent(va1.x) | has_sent(va1.y) | has_sent(va1.z) | has_sent(va1.w);
        if (!bad) break;
      }
      __builtin_amdgcn_sched_barrier(0);
      *(uint4*)(hAc + lds0) = va0;
      *(uint4*)(hAc + lds1) = va1;
      __syncthreads();

      // gates: 8 independent chains of 4 MFMA, then pairwise tree add
      f32x4 q0 = {0.f,0.f,0.f,0.f}, q1 = q0, q2 = q0, q3 = q0, q4 = q0, q5 = q0, q6 = q0, q7 = q0;
      {
        int arow = lane & 15;
        int sw = (arow & 7) << 4;
        int kg16 = (lane >> 4) * 16;
#pragma unroll
        for (int kt = 0; kt < 16; kt += 4){
          int ab0 = (arow * 1024 + kt * 64 + kg16) ^ sw;
          int ab1 = (arow * 1024 + (kt + 1) * 64 + kg16) ^ sw;
          int ab2 = (arow * 1024 + (kt + 2) * 64 + kg16) ^ sw;
          int ab3 = (arow * 1024 + (kt + 3) * 64 + kg16) ^ sw;
          s16x8 f0 = *(const s16x8*)(hAc + ab0);
          s16x8 f1 = *(const s16x8*)(hAc + ab1);
          s16x8 f2 = *(const s16x8*)(hAc + ab2);
          s16x8 f3 = *(const s16x8*)(hAc + ab3);
          q0 = __builtin_amdgcn_mfma_f32_16x16x32_bf16(f0, Bf0[kt], q0, 0, 0, 0);
          q1 = __builtin_amdgcn_mfma_f32_16x16x32_bf16(f0, Bf1[kt], q1, 0, 0, 0);
          q2 = __builtin_amdgcn_mfma_f32_16x16x32_bf16(f1, Bf0[kt + 1], q2, 0, 0, 0);
          q3 = __builtin_amdgcn_mfma_f32_16x16x32_bf16(f1, Bf1[kt + 1], q3, 0, 0, 0);
          q4 = __builtin_amdgcn_mfma_f32_16x16x32_bf16(f2, Bf0[kt + 2], q4, 0, 0, 0);
          q5 = __builtin_amdgcn_mfma_f32_16x16x32_bf16(f2, Bf1[kt + 2], q5, 0, 0, 0);
          q6 = __builtin_amdgcn_mfma_f32_16x16x32_bf16(f3, Bf0[kt + 3], q6, 0, 0, 0);
          q7 = __builtin_amdgcn_mfma_f32_16x16x32_bf16(f3, Bf1[kt + 3], q7, 0, 0, 0);
        }
      }
      f32x4 acc0 = (q0 + q2) + (q4 + q6), acc1 = (q1 + q3) + (q5 + q7);
      // same-wave gate exchange (program order + lgkmcnt, no barrier); stride-40 layout
      if (lane < 32){
#pragma unroll
        for (int r = 0; r < 4; ++r){
          glw[(bb + r) * 40 + woff] = acc0[r];
          glw[(bb + r) * 40 + 20 + woff] = acc1[r];
        }
      }
      gi = glw[b_own * 40 + jj]      + xwi;
      gf = glw[b_own * 40 + 10 + jj] + xwf;
      gg = glw[b_own * 40 + 20 + jj] + xwg;
      go = glw[b_own * 40 + 30 + jj] + xwo;
    }
    creg = sigm(gf) * creg + sigm(gi) * tanh_f(gg);
    float hv = sigm(go) * tanh_f(creg);
    unsigned short* hp = Hb + ((long)b_own * S_ + s) * RNN_ + dir * HD_ + j_own;
    unsigned hd = (unsigned)f2bf(hv);
    asm volatile("global_store_short %0, %1, off sc0 sc1"
                 :: "v"(hp), "v"(hd) : "memory");
    if (t + 1 < S_){
      int sn = dir ? (s - 1) : (s + 1);
      long base = ((long)sn * 8 + b_own) * G4_ + j_own;
      xwi = bf2f(xw[base]); xwf = bf2f(xw[base + 512]);
      xwg = bf2f(xw[base + 1024]); xwo = bf2f(xw[base + 1536]);
    }
  }
}

// ---------------- fused softmax (over s) + logits ----------------
__global__ __launch_bounds__(256)
void k_softmax_logits(float* __restrict__ alpha, const unsigned short* __restrict__ HOt,
                      const float* __restrict__ Ob, float* __restrict__ logits){
  const int lane = threadIdx.x & 63, wv = threadIdx.x >> 6;
  long row = (long)blockIdx.x * 4 + wv;       // row = b*C + c
  float* a = alpha + row * (long)S_;
  const unsigned short* h = HOt + row * (long)S_;
  float v[32];
  float mx = -1e30f;
#pragma unroll
  for (int jj = 0; jj < 8; ++jj){
    f32x4 t = *(const f32x4*)(a + jj * 256 + lane * 4);
#pragma unroll
    for (int r = 0; r < 4; ++r){ v[jj * 4 + r] = t[r]; mx = fmaxf(mx, t[r]); }
  }
#pragma unroll
  for (int o = 32; o > 0; o >>= 1) mx = fmaxf(mx, __shfl_xor(mx, o));
  float sum = 0.f;
#pragma unroll
  for (int i = 0; i < 32; ++i){ v[i] = __expf(v[i] - mx); sum += v[i]; }
#pragma unroll
  for (int o = 32; o > 0; o >>= 1) sum += __shfl_xor(sum, o);
  float inv = 1.f / sum;
  float dot = 0.f;
#pragma unroll
  for (int jj = 0; jj < 8; ++jj){
    s16x4 hv = *(const s16x4*)(h + jj * 256 + lane * 4);
    f32x4 av;
#pragma unroll
    for (int r = 0; r < 4; ++r){
      float al = v[jj * 4 + r] * inv;
      av[r] = al;
      dot += al * bf2f((unsigned short)hv[r]);
    }
    *(f32x4*)(a + jj * 256 + lane * 4) = av;
  }
#pragma unroll
  for (int o = 32; o > 0; o >>= 1) dot += __shfl_xor(dot, o);
  if (lane == 0){
    int c = (int)(row % C_);
    logits[row] = dot + Ob[c];
  }
}

// ---------------- host ----------------
extern "C" void kernel_launch(void* const* d_in, const int* in_sizes, int n_in,
                              void* d_out, int out_size, void* d_ws, size_t ws_size,
                              hipStream_t stream){
  const int*   text  = (const int*)d_in[0];
  const float* emb   = (const float*)d_in[2];
  const float* Wih_f = (const float*)d_in[3];
  const float* Whh_f = (const float*)d_in[4];
  const float* b_f   = (const float*)d_in[5];
  const float* Wih_b = (const float*)d_in[6];
  const float* Whh_b = (const float*)d_in[7];
  const float* b_b   = (const float*)d_in[8];
  const float* Ww    = (const float*)d_in[9];
  const float* Qw    = (const float*)d_in[10];
  const float* Ow    = (const float*)d_in[11];
  const float* Ob    = (const float*)d_in[12];

  char* ws = (char*)d_ws;
  long o = 0;
  unsigned short* wWihF = (unsigned short*)(ws + o); o += 2048L * 320 * 2;
  unsigned short* wWihB = (unsigned short*)(ws + o); o += 2048L * 320 * 2;
  unsigned short* wWw   = (unsigned short*)(ws + o); o += 512L * 1024 * 2;
  unsigned short* wQw   = (unsigned short*)(ws + o); o += 8960L * 512 * 2;
  unsigned short* wOw   = (unsigned short*)(ws + o); o += 8960L * 1024 * 2;
  unsigned short* wH    = (unsigned short*)(ws + o); o += 8L * 2048 * 1024 * 2;
  unsigned short* wZ    = (unsigned short*)(ws + o); o += 16384L * 512 * 2;
  char* regA = ws + o;                                // reused region
  unsigned short* wXe  = (unsigned short*)regA;                         // [16384][320]
  unsigned short* wXw  = (unsigned short*)(regA + 16384L * 320 * 2);    // [2][16384][2048]
  unsigned short* wHOt = (unsigned short*)regA;                         // [8][8921][2048] (after LSTM)

  float* logits = (float*)d_out;
  float* alpha  = logits + 8L * C_;    // [8][8921][2048], also holds raw scores

  // re-arm the data-as-flag sentinel every launch (graph-replay safe)
  hipMemsetAsync(wH, 0xFF, 8L * 2048 * 1024 * 2, stream);
  k_cvt_pad<<<2048, 256, 0, stream>>>(Wih_f, wWihF, 2048, 300, 320);
  k_cvt_pad<<<2048, 256, 0, stream>>>(Wih_b, wWihB, 2048, 300, 320);
  k_cvt_pad<<<512,  256, 0, stream>>>(Ww, wWw, 512, 1024, 1024);
  k_cvt_pad<<<8960, 256, 0, stream>>>(Qw, wQw, 8921, 512, 512);
  k_cvt_pad<<<8960, 256, 0, stream>>>(Ow, wOw, 8921, 1024, 1024);
  k_embed<<<16384, 256, 0, stream>>>(text, emb, wXe);

  // xw[dir] = xe @ Wih^T + b  -> bf16 [16384][2048]
  k_gemm_bt<2><<<dim3(16, 128, 1), 256, 0, stream>>>(wXe, wWihF, wXw, 2048, 320, 16384, 0, 0, 0, b_f);
  k_gemm_bt<2><<<dim3(16, 128, 1), 256, 0, stream>>>(wXe, wWihB, wXw + 16384L * 2048, 2048, 320, 16384, 0, 0, 0, b_b);

  k_lstm<<<32, 256, 0, stream>>>(wXw, Whh_f, Whh_b, wH);

  // Z = tanh(H @ Ww^T)  [16384][512] bf16
  k_gemm_bt<1><<<dim3(4, 128, 1), 256, 0, stream>>>(wH, wWw, wZ, 512, 1024, 16384, 0, 0, 0, nullptr);
  // scores[b] = Qw @ Z[b]^T  -> fp32 into alpha region
  k_gemm_bt<0><<<dim3(16, 70, 8), 256, 0, stream>>>(wQw, wZ, alpha, 2048, 512, C_, 0, 2048L * 512, (long)C_ * 2048, nullptr);
  // HOt[b] = Ow @ H[b]^T  -> bf16
  k_gemm_bt<3><<<dim3(16, 70, 8), 256, 0, stream>>>(wOw, wH, wHOt, 2048, 1024, C_, 0, 2048L * 1024, (long)C_ * 2048, nullptr);

  k_softmax_logits<<<17842, 256, 0, stream>>>(alpha, wHOt, Ob, logits);
}